// Round 1
// baseline (666.852 us; speedup 1.0000x reference)
//
#include <hip/hip_runtime.h>

typedef unsigned short u16;
typedef unsigned int u32;
typedef __bf16 bf16x8 __attribute__((ext_vector_type(8)));
typedef float f32x4 __attribute__((ext_vector_type(4)));

// ---------- numerics helpers ----------

// round-to-nearest onto {0,.5,1,1.5,2,3,4,6}, ties (at mids) round UP
// (matches jnp.searchsorted(side='right') with strict '<' comparisons)
__device__ __forceinline__ float fp4_round_f(float v) {
  float a = fabsf(v);
  a = fminf(a, 6.0f);
  float r;
  if      (a < 0.25f) r = 0.0f;
  else if (a < 0.75f) r = 0.5f;
  else if (a < 1.25f) r = 1.0f;
  else if (a < 1.75f) r = 1.5f;
  else if (a < 2.5f)  r = 2.0f;
  else if (a < 3.5f)  r = 3.0f;
  else if (a < 5.0f)  r = 4.0f;
  else                r = 6.0f;
  return copysignf(r, v);
}

// f32 -> e4m3fn -> f32 roundtrip for r in [0, 448], RNE
__device__ __forceinline__ float e4m3_rne(float r) {
  if (r < 0.015625f) {            // subnormal range: grid step 2^-9
    return rintf(r * 512.0f) * (1.0f / 512.0f);
  }
  u32 u = __float_as_uint(r);
  u32 lsb = (u >> 20) & 1u;       // keep 3 mantissa bits, drop 20, RNE
  u += 0x7FFFFu + lsb;
  u &= 0xFFF00000u;
  return __uint_as_float(u);
}

__device__ __forceinline__ void gload_lds16(const u16* g, void* l) {
  __builtin_amdgcn_global_load_lds(
      (const __attribute__((address_space(1))) void*)g,
      (__attribute__((address_space(3))) void*)l, 16, 0, 0);
}

// ---------- global amax (abs) ----------

__global__ void __launch_bounds__(256) amax_kernel(const float4* __restrict__ p,
                                                   int n4, u32* __restrict__ out) {
  float m = 0.0f;
  int stride = gridDim.x * blockDim.x;
  for (int i = blockIdx.x * blockDim.x + threadIdx.x; i < n4; i += stride) {
    float4 v = p[i];
    m = fmaxf(m, fmaxf(fmaxf(fabsf(v.x), fabsf(v.y)), fmaxf(fabsf(v.z), fabsf(v.w))));
  }
#pragma unroll
  for (int o = 32; o > 0; o >>= 1) m = fmaxf(m, __shfl_xor(m, o));
  if ((threadIdx.x & 63) == 0) atomicMax(out, __float_as_uint(m));  // vals >= 0: uint cmp == float cmp
}

// ---------- quantize x: 1 thread per 16-elem block (last-dim blocks) ----------

__global__ void __launch_bounds__(256) quant_x_kernel(const float* __restrict__ x,
                                                      const float* __restrict__ scal,
                                                      u16* __restrict__ q, int nblk) {
  int b = blockIdx.x * 256 + threadIdx.x;
  if (b >= nblk) return;
  const float4* px = (const float4*)(x + (size_t)b * 16);
  float4 v[4];
  v[0] = px[0]; v[1] = px[1]; v[2] = px[2]; v[3] = px[3];
  float am = 0.0f;
  const float* vf = (const float*)v;
#pragma unroll
  for (int i = 0; i < 16; ++i) am = fmaxf(am, fabsf(vf[i]));

  float g = scal[0] / 2688.0f;                       // g_scale = amax/(448*6)
  float ratio = fminf(fmaxf((am / 6.0f) / g, 0.0f), 448.0f);
  float sq = e4m3_rne(ratio);                        // e4m3 block scale (f32 value)
  float s = sq * g;                                  // full scale, as reference computes it
  float ss = s > 0.0f ? s : 1.0f;

  union { u16 h[16]; uint4 v4[2]; } ou;
#pragma unroll
  for (int i = 0; i < 16; ++i) {
    float qv = fp4_round_f(vf[i] / ss) * sq;         // exact in bf16 (<=6 sig bits)
    ou.h[i] = (u16)(__float_as_uint(qv) >> 16);      // exact truncation to bf16
  }
  uint4* qd = (uint4*)(q + (size_t)b * 16);
  qd[0] = ou.v4[0];
  qd[1] = ou.v4[1];
}

// ---------- quantize w: 1 wave per 16x16 block ----------

__global__ void __launch_bounds__(256) quant_w_kernel(const float* __restrict__ w,
                                                      const float* __restrict__ scal,
                                                      u16* __restrict__ q, int ntc, int K) {
  int wav = blockIdx.x * 4 + (threadIdx.x >> 6);
  int lane = threadIdx.x & 63;
  int tr = wav / ntc, tc = wav % ntc;
  int r = lane >> 2, c = (lane & 3) * 4;
  size_t off = (size_t)(tr * 16 + r) * K + tc * 16 + c;
  float4 v = *(const float4*)(w + off);
  float am = fmaxf(fmaxf(fabsf(v.x), fabsf(v.y)), fmaxf(fabsf(v.z), fabsf(v.w)));
#pragma unroll
  for (int o = 32; o > 0; o >>= 1) am = fmaxf(am, __shfl_xor(am, o));

  float g = scal[1] / 2688.0f;
  float ratio = fminf(fmaxf((am / 6.0f) / g, 0.0f), 448.0f);
  float sq = e4m3_rne(ratio);
  float s = sq * g;
  float ss = s > 0.0f ? s : 1.0f;

  float vf[4] = {v.x, v.y, v.z, v.w};
  union { u16 h[4]; uint2 v2; } ou;
#pragma unroll
  for (int i = 0; i < 4; ++i) {
    float qv = fp4_round_f(vf[i] / ss) * sq;
    ou.h[i] = (u16)(__float_as_uint(qv) >> 16);
  }
  *(uint2*)(q + off) = ou.v2;
}

// ---------- bf16 GEMM: C = Qx[M][K] * Qw[N][K]^T, epilogue: *gs + bias ----------

#define BM 128
#define BN 128
#define BK 32

__global__ void __launch_bounds__(256) gemm_kernel(const u16* __restrict__ A,
                                                   const u16* __restrict__ B,
                                                   const float* __restrict__ bias,
                                                   const float* __restrict__ scal,
                                                   float* __restrict__ out,
                                                   int M, int N, int K) {
  __shared__ __align__(16) u16 As[BM * BK];
  __shared__ __align__(16) u16 Bs[BN * BK];

  // bijective XCD-aware swizzle (m204 variant)
  int nwg = gridDim.x;
  int bid = blockIdx.x;
  int q8 = nwg >> 3, r8 = nwg & 7;
  int xcd = bid & 7, loc = bid >> 3;
  int wg = (xcd < r8 ? xcd * (q8 + 1) : r8 * (q8 + 1) + (xcd - r8) * q8) + loc;
  int ntn = N / BN;
  int tm = wg / ntn, tn = wg % ntn;
  int brow = tm * BM, bcol = tn * BN;

  int tid = threadIdx.x;
  int wid = tid >> 6, lane = tid & 63;

  // staging: per wave 2x 1KB chunks for A and B tiles (8KB each), LDS dest is
  // wave-uniform base + lane*16 (global_load_lds semantics)
  const u16* gA[2];
  const u16* gB[2];
  char* lA[2];
  char* lB[2];
#pragma unroll
  for (int t = 0; t < 2; ++t) {
    int off = wid * 2048 + t * 1024 + lane * 16;   // byte offset in 8KB tile
    int rr = off >> 6;                             // row (64B per row of BK=32 bf16)
    int cc = (off & 63) >> 1;                      // element col within BK
    gA[t] = A + (size_t)(brow + rr) * K + cc;
    gB[t] = B + (size_t)(bcol + rr) * K + cc;
    lA[t] = (char*)As + wid * 2048 + t * 1024;
    lB[t] = (char*)Bs + wid * 2048 + t * 1024;
  }

  int wr = wid >> 1, wc = wid & 1;                 // 2x2 wave grid, 64x64 out each
  int fr = lane & 15, fk = (lane >> 4) * 8;
  const char* pAf = (const char*)As + (wr * 64 + fr) * (BK * 2) + fk * 2;
  const char* pBf = (const char*)Bs + (wc * 64 + fr) * (BK * 2) + fk * 2;

  f32x4 zero = {0.0f, 0.0f, 0.0f, 0.0f};
  f32x4 acc[4][4];
#pragma unroll
  for (int m = 0; m < 4; ++m)
#pragma unroll
    for (int n = 0; n < 4; ++n) acc[m][n] = zero;

  for (int kt = 0; kt < K; kt += BK) {
    __syncthreads();                               // LDS reads of prev iter done
#pragma unroll
    for (int t = 0; t < 2; ++t) {
      gload_lds16(gA[t] + kt, lA[t]);
      gload_lds16(gB[t] + kt, lB[t]);
    }
    __syncthreads();                               // vmcnt(0) drain + barrier
    bf16x8 a[4], b[4];
#pragma unroll
    for (int m = 0; m < 4; ++m) a[m] = *(const bf16x8*)(pAf + m * 1024);
#pragma unroll
    for (int n = 0; n < 4; ++n) b[n] = *(const bf16x8*)(pBf + n * 1024);
#pragma unroll
    for (int m = 0; m < 4; ++m)
#pragma unroll
      for (int n = 0; n < 4; ++n)
        acc[m][n] = __builtin_amdgcn_mfma_f32_16x16x32_bf16(a[m], b[n], acc[m][n], 0, 0, 0);
  }

  // epilogue: y = acc * (g_x * g_w) + bias
  float gs = (scal[0] / 2688.0f) * (scal[1] / 2688.0f);
#pragma unroll
  for (int n = 0; n < 4; ++n) {
    int col = bcol + wc * 64 + n * 16 + fr;        // C/D: col = lane&15
    float bv = bias[col];
#pragma unroll
    for (int m = 0; m < 4; ++m) {
      int row0 = brow + wr * 64 + m * 16 + ((lane >> 4) << 2);  // row = (lane>>4)*4 + j
      f32x4 a4 = acc[m][n];
#pragma unroll
      for (int j = 0; j < 4; ++j)
        out[(size_t)(row0 + j) * N + col] = a4[j] * gs + bv;
    }
  }
}

// ---------- launch ----------

extern "C" void kernel_launch(void* const* d_in, const int* in_sizes, int n_in,
                              void* d_out, int out_size, void* d_ws, size_t ws_size,
                              hipStream_t stream) {
  const float* x = (const float*)d_in[0];
  const float* w = (const float*)d_in[1];
  const float* bias = (const float*)d_in[2];
  float* out = (float*)d_out;

  const int DOUT = in_sizes[2];        // 4096
  const int K = in_sizes[1] / DOUT;    // 4096
  const int M = in_sizes[0] / K;       // 8192
  const int N = DOUT;

  // workspace layout: [0,8): amax scalars; [256, 256+N*K*2): Qw; then Qx (M*K*2)
  float* scal = (float*)d_ws;
  u16* qw = (u16*)((char*)d_ws + 256);
  u16* qx = (u16*)((char*)d_ws + 256 + (size_t)N * K * 2);

  hipMemsetAsync(scal, 0, 2 * sizeof(float), stream);
  amax_kernel<<<2048, 256, 0, stream>>>((const float4*)x, (M * K) / 4, (u32*)scal);
  amax_kernel<<<2048, 256, 0, stream>>>((const float4*)w, (N * K) / 4, ((u32*)scal) + 1);

  int nblk = (M * K) / 16;
  quant_x_kernel<<<(nblk + 255) / 256, 256, 0, stream>>>(x, scal, qx, nblk);

  int ntiles = (N / 16) * (K / 16);
  quant_w_kernel<<<ntiles / 4, 256, 0, stream>>>(w, scal, qw, K / 16, K);

  gemm_kernel<<<(M / BM) * (N / BN), 256, 0, stream>>>(qx, qw, bias, scal, out, M, N, K);
}

// Round 2
// 348.645 us; speedup vs baseline: 1.9127x; 1.9127x over previous
//
#include <hip/hip_runtime.h>

typedef unsigned short u16;
typedef unsigned int u32;
typedef __bf16 bf16x8 __attribute__((ext_vector_type(8)));
typedef float f32x4 __attribute__((ext_vector_type(4)));

// ---------- numerics helpers ----------

// f32 -> e4m3fn -> f32 roundtrip for r in [0, 448], RNE
__device__ __forceinline__ float e4m3_rne(float r) {
  if (r < 0.015625f) {            // subnormal range: grid step 2^-9
    return rintf(r * 512.0f) * (1.0f / 512.0f);
  }
  u32 u = __float_as_uint(r);
  u32 lsb = (u >> 20) & 1u;       // keep 3 mantissa bits, drop 20, RNE
  u += 0x7FFFFu + lsb;
  u &= 0xFFF00000u;
  return __uint_as_float(u);
}

// fp4 level select against per-block thresholds t[7] = mids * ss.
// Equivalent to fp4_round(x/ss) up to 1-ulp boundary cases; ties round up.
__device__ __forceinline__ float fp4_level(float a, const float* t) {
  return a < t[3] ? (a < t[1] ? (a < t[0] ? 0.0f : 0.5f)
                              : (a < t[2] ? 1.0f : 1.5f))
                  : (a < t[5] ? (a < t[4] ? 2.0f : 3.0f)
                              : (a < t[6] ? 4.0f : 6.0f));
}

__device__ __forceinline__ void gload_lds16(const u16* g, void* l) {
  __builtin_amdgcn_global_load_lds(
      (const __attribute__((address_space(1))) void*)g,
      (__attribute__((address_space(3))) void*)l, 16, 0, 0);
}

// ---------- amax partials (no atomics) ----------

__global__ void __launch_bounds__(256) amax_part_kernel(const float4* __restrict__ p,
                                                        int n4, float* __restrict__ part) {
  float m = 0.0f;
  int stride = gridDim.x * 256;
  for (int i = blockIdx.x * 256 + threadIdx.x; i < n4; i += stride) {
    float4 v = p[i];
    m = fmaxf(m, fmaxf(fmaxf(fabsf(v.x), fabsf(v.y)), fmaxf(fabsf(v.z), fabsf(v.w))));
  }
#pragma unroll
  for (int o = 32; o > 0; o >>= 1) m = fmaxf(m, __shfl_xor(m, o));
  __shared__ float red[4];
  int wid = threadIdx.x >> 6, lane = threadIdx.x & 63;
  if (lane == 0) red[wid] = m;
  __syncthreads();
  if (threadIdx.x == 0)
    part[blockIdx.x] = fmaxf(fmaxf(red[0], red[1]), fmaxf(red[2], red[3]));
}

__global__ void __launch_bounds__(256) finalize_kernel(const float* __restrict__ px,
                                                       const float* __restrict__ pw,
                                                       float* __restrict__ scal,
                                                       int nx, int nw) {
  int tid = threadIdx.x;
  float mx = 0.0f, mw = 0.0f;
  for (int i = tid; i < nx; i += 256) mx = fmaxf(mx, px[i]);
  for (int i = tid; i < nw; i += 256) mw = fmaxf(mw, pw[i]);
#pragma unroll
  for (int o = 32; o > 0; o >>= 1) {
    mx = fmaxf(mx, __shfl_xor(mx, o));
    mw = fmaxf(mw, __shfl_xor(mw, o));
  }
  __shared__ float rx[4], rw[4];
  int wid = tid >> 6, lane = tid & 63;
  if (lane == 0) { rx[wid] = mx; rw[wid] = mw; }
  __syncthreads();
  if (tid == 0) {
    scal[0] = fmaxf(fmaxf(rx[0], rx[1]), fmaxf(rx[2], rx[3]));
    scal[1] = fmaxf(fmaxf(rw[0], rw[1]), fmaxf(rw[2], rw[3]));
  }
}

// ---------- quantize x: 1 thread per 16-elem block, threshold compare ----------

__global__ void __launch_bounds__(256) quant_x_kernel(const float* __restrict__ x,
                                                      const float* __restrict__ scal,
                                                      u16* __restrict__ q, int nblk) {
  int b = blockIdx.x * 256 + threadIdx.x;
  if (b >= nblk) return;
  const float4* px = (const float4*)(x + (size_t)b * 16);
  float4 v[4];
  v[0] = px[0]; v[1] = px[1]; v[2] = px[2]; v[3] = px[3];
  float am = 0.0f;
  const float* vf = (const float*)v;
#pragma unroll
  for (int i = 0; i < 16; ++i) am = fmaxf(am, fabsf(vf[i]));

  float g = scal[0] / 2688.0f;                       // g_scale = amax/(448*6)
  float ratio = fminf(fmaxf((am / 6.0f) / g, 0.0f), 448.0f);
  float sq = e4m3_rne(ratio);                        // e4m3 block scale (f32 value)
  float s = sq * g;
  float ss = s > 0.0f ? s : 1.0f;
  float t[7] = {0.25f * ss, 0.75f * ss, 1.25f * ss, 1.75f * ss,
                2.5f * ss, 3.5f * ss, 5.0f * ss};

  union { u16 h[16]; uint4 v4[2]; } ou;
#pragma unroll
  for (int i = 0; i < 16; ++i) {
    float qv = copysignf(fp4_level(fabsf(vf[i]), t) * sq, vf[i]);  // exact in bf16
    ou.h[i] = (u16)(__float_as_uint(qv) >> 16);
  }
  uint4* qd = (uint4*)(q + (size_t)b * 16);
  qd[0] = ou.v4[0];
  qd[1] = ou.v4[1];
}

// ---------- quantize w: 1 wave per 16x16 block ----------

__global__ void __launch_bounds__(256) quant_w_kernel(const float* __restrict__ w,
                                                      const float* __restrict__ scal,
                                                      u16* __restrict__ q, int ntc, int K) {
  int wav = blockIdx.x * 4 + (threadIdx.x >> 6);
  int lane = threadIdx.x & 63;
  int tr = wav / ntc, tc = wav % ntc;
  int r = lane >> 2, c = (lane & 3) * 4;
  size_t off = (size_t)(tr * 16 + r) * K + tc * 16 + c;
  float4 v = *(const float4*)(w + off);
  float am = fmaxf(fmaxf(fabsf(v.x), fabsf(v.y)), fmaxf(fabsf(v.z), fabsf(v.w)));
#pragma unroll
  for (int o = 32; o > 0; o >>= 1) am = fmaxf(am, __shfl_xor(am, o));

  float g = scal[1] / 2688.0f;
  float ratio = fminf(fmaxf((am / 6.0f) / g, 0.0f), 448.0f);
  float sq = e4m3_rne(ratio);
  float s = sq * g;
  float ss = s > 0.0f ? s : 1.0f;
  float t[7] = {0.25f * ss, 0.75f * ss, 1.25f * ss, 1.75f * ss,
                2.5f * ss, 3.5f * ss, 5.0f * ss};

  float vf[4] = {v.x, v.y, v.z, v.w};
  union { u16 h[4]; uint2 v2; } ou;
#pragma unroll
  for (int i = 0; i < 4; ++i) {
    float qv = copysignf(fp4_level(fabsf(vf[i]), t) * sq, vf[i]);
    ou.h[i] = (u16)(__float_as_uint(qv) >> 16);
  }
  *(uint2*)(q + off) = ou.v2;
}

// ---------- bf16 GEMM, 256x256 tile, BK=64, 8 waves, 8-phase schedule ----------
// LDS: 2 buffers x (A 256x64 + B 256x64) bf16 = 128 KiB (dynamic).
// Swizzle: element (row, byte b in row) stored at row*128 + (b ^ ((row&7)<<4)).
// Staged via global_load_lds with inverse-swizzled per-lane GLOBAL source
// (linear LDS dest), read back with the same XOR on the ds_read address.

#define BM 256
#define BN 256
#define BK 64

__global__ void __launch_bounds__(512, 2) gemm_kernel(const u16* __restrict__ A,
                                                      const u16* __restrict__ B,
                                                      const float* __restrict__ bias,
                                                      const float* __restrict__ scal,
                                                      float* __restrict__ out,
                                                      int M, int N, int K) {
  extern __shared__ char lds[];   // [2][A:32768 | B:32768]
  const int tid = threadIdx.x;
  const int wid = tid >> 6, lane = tid & 63;
  const int fr = lane & 15, fc = lane >> 4;
  const int wm = wid >> 2, wn = wid & 3;     // 2 x 4 wave grid; 128x64 out per wave
  const int sw = (fr & 7) << 4;              // read-side XOR (row&7 == fr&7 for all frags)

  // bijective XCD-aware block swizzle
  int nwg = gridDim.x, bid = blockIdx.x;
  int q8 = nwg >> 3, r8 = nwg & 7;
  int xcd = bid & 7, loc = bid >> 3;
  int wg = (xcd < r8 ? xcd * (q8 + 1) : r8 * (q8 + 1) + (xcd - r8) * q8) + loc;
  int ntn = N / BN;
  int tm = wg / ntn, tn = wg % ntn;
  int brow = tm * BM, bcol = tn * BN;

  // staging: thread tid fills LDS bytes [s*8192 + tid*16, +16) of a 32 KB tile.
  // LDS row = s*64 + tid/8; within-row chunk = (tid&7)*16, inverse-swizzled source.
  const int srow = tid >> 3;                               // + s*64
  const int scol = ((((tid & 7) << 4) ^ ((srow & 7) << 4)) >> 1);  // element col 0..63
  const u16* gA = A + (size_t)(brow + srow) * K + scol;
  const u16* gB = B + (size_t)(bcol + srow) * K + scol;
  const size_t K64 = (size_t)K * 64;
  const int ldsOff = wid << 10;                            // wave slot in 8 KB chunk

#define STAGE_A(bufbase, ktoff) do {                                         \
    _Pragma("unroll") for (int s_ = 0; s_ < 4; ++s_)                         \
      gload_lds16(gA + (size_t)s_ * K64 + (ktoff), (bufbase) + s_ * 8192 + ldsOff); \
  } while (0)
#define STAGE_B(bufbase, ktoff) do {                                         \
    _Pragma("unroll") for (int s_ = 0; s_ < 4; ++s_)                         \
      gload_lds16(gB + (size_t)s_ * K64 + (ktoff), (bufbase) + s_ * 8192 + ldsOff); \
  } while (0)

// A frag (qm, j, k): LDS row = wm*128 + qm*64 + j*16 + fr, chunk byte (fc*16 + k*64) ^ sw
#define LOAD_A(dst, qm)                                                      \
  _Pragma("unroll") for (int j_ = 0; j_ < 4; ++j_)                           \
  _Pragma("unroll") for (int k_ = 0; k_ < 2; ++k_)                           \
    dst[j_][k_] = *(const bf16x8*)(abuf + ((wm * 128 + (qm) * 64 + j_ * 16 + fr) * 128 \
                                           + (((fc << 4) + (k_ << 6)) ^ sw)));
#define LOAD_B(dst, qn)                                                      \
  _Pragma("unroll") for (int j_ = 0; j_ < 2; ++j_)                           \
  _Pragma("unroll") for (int k_ = 0; k_ < 2; ++k_)                           \
    dst[j_][k_] = *(const bf16x8*)(bbuf + ((wn * 64 + (qn) * 32 + j_ * 16 + fr) * 128 \
                                           + (((fc << 4) + (k_ << 6)) ^ sw)));

#define MMA(qm, qn, af, bf)                                                  \
  _Pragma("unroll") for (int j_ = 0; j_ < 4; ++j_)                           \
  _Pragma("unroll") for (int n_ = 0; n_ < 2; ++n_)                           \
  _Pragma("unroll") for (int k_ = 0; k_ < 2; ++k_)                           \
    acc[(qm) * 4 + j_][(qn) * 2 + n_] = __builtin_amdgcn_mfma_f32_16x16x32_bf16( \
        af[j_][k_], bf[n_][k_], acc[(qm) * 4 + j_][(qn) * 2 + n_], 0, 0, 0);

#define PHASE_MID()                                          \
  __builtin_amdgcn_s_barrier();                              \
  asm volatile("s_waitcnt lgkmcnt(0)" ::: "memory");         \
  __builtin_amdgcn_sched_barrier(0);                         \
  __builtin_amdgcn_s_setprio(1);
#define PHASE_END()                                          \
  __builtin_amdgcn_s_setprio(0);                             \
  __builtin_amdgcn_s_barrier();

  f32x4 acc[8][4];
  f32x4 zero = {0.0f, 0.0f, 0.0f, 0.0f};
#pragma unroll
  for (int m = 0; m < 8; ++m)
#pragma unroll
    for (int n = 0; n < 4; ++n) acc[m][n] = zero;

  const int NT = K / BK;

  // prologue: stage tile 0 into buffer 0
  STAGE_A(lds, 0);
  STAGE_B(lds + 32768, 0);
  asm volatile("s_waitcnt vmcnt(0)" ::: "memory");
  __builtin_amdgcn_s_barrier();

  bf16x8 a[4][2], b0[2][2], b1[2][2];
  int cur = 0;
  for (int t = 0; t < NT; ++t) {
    const char* abuf = lds + cur * 65536;
    const char* bbuf = abuf + 32768;
    char* sbuf = lds + (cur ^ 1) * 65536;
    const bool pf = (t + 1 < NT);
    const int ktn = (t + 1) * BK;

    // phase 1: quad (qm=0, qn=0) — 12 ds_reads + A prefetch
    LOAD_A(a, 0);
    LOAD_B(b0, 0);
    if (pf) STAGE_A(sbuf, ktn);
    PHASE_MID();
    MMA(0, 0, a, b0);
    PHASE_END();

    // phase 2: quad (0,1) — 4 ds_reads + B prefetch
    LOAD_B(b1, 1);
    if (pf) STAGE_B(sbuf + 32768, ktn);
    PHASE_MID();
    MMA(0, 1, a, b1);
    PHASE_END();

    // phase 3: quad (1,1) — 8 ds_reads
    LOAD_A(a, 1);
    PHASE_MID();
    MMA(1, 1, a, b1);
    PHASE_END();

    // phase 4: quad (1,0) — no reads; tile-boundary drain
    __builtin_amdgcn_s_setprio(1);
    MMA(1, 0, a, b0);
    __builtin_amdgcn_s_setprio(0);
    asm volatile("s_waitcnt vmcnt(0)" ::: "memory");
    __builtin_amdgcn_s_barrier();
    cur ^= 1;
  }

  // epilogue: y = acc * (g_x * g_w) + bias
  float gs = (scal[0] / 2688.0f) * (scal[1] / 2688.0f);
#pragma unroll
  for (int n = 0; n < 4; ++n) {
    int col = bcol + wn * 64 + n * 16 + fr;        // C/D: col = lane&15
    float bv = bias[col];
#pragma unroll
    for (int m = 0; m < 8; ++m) {
      int row0 = brow + wm * 128 + m * 16 + (fc << 2);  // row = (lane>>4)*4 + j
      f32x4 v = acc[m][n];
#pragma unroll
      for (int j = 0; j < 4; ++j)
        out[(size_t)(row0 + j) * N + col] = v[j] * gs + bv;
    }
  }
}

// ---------- launch ----------

extern "C" void kernel_launch(void* const* d_in, const int* in_sizes, int n_in,
                              void* d_out, int out_size, void* d_ws, size_t ws_size,
                              hipStream_t stream) {
  const float* x = (const float*)d_in[0];
  const float* w = (const float*)d_in[1];
  const float* bias = (const float*)d_in[2];
  float* out = (float*)d_out;

  const int DOUT = in_sizes[2];        // 4096
  const int K = in_sizes[1] / DOUT;    // 4096
  const int M = in_sizes[0] / K;       // 8192
  const int N = DOUT;

  // ws layout: [0,8): scal; [256, 256+6KB): amax partials; [8192, +32MB): Qw; then Qx
  float* scal = (float*)d_ws;
  float* px = (float*)((char*)d_ws + 256);          // 1024 floats
  float* pw = px + 1024;                            // 512 floats
  u16* qw = (u16*)((char*)d_ws + 8192);
  u16* qx = (u16*)((char*)d_ws + 8192 + (size_t)N * K * 2);

  amax_part_kernel<<<1024, 256, 0, stream>>>((const float4*)x, (M * K) / 4, px);
  amax_part_kernel<<<512, 256, 0, stream>>>((const float4*)w, (N * K) / 4, pw);
  finalize_kernel<<<1, 256, 0, stream>>>(px, pw, scal, 1024, 512);

  int nblk = (M * K) / 16;
  quant_x_kernel<<<(nblk + 255) / 256, 256, 0, stream>>>(x, scal, qx, nblk);

  int ntiles = (N / 16) * (K / 16);
  quant_w_kernel<<<ntiles / 4, 256, 0, stream>>>(w, scal, qw, K / 16, K);

  gemm_kernel<<<(M / BM) * (N / BN), 512, 131072, stream>>>(qx, qw, bias, scal, out,
                                                            M, N, K);
}